// Round 1
// baseline (177.474 us; speedup 1.0000x reference)
//
#include <hip/hip_runtime.h>

// ModulatedDeformConv2d fwd, fp32 baseline.
// B=4 C=64 H=W=96 O=64 K=3x3 stride=1 pad=1 dil=1 groups=1 dg=1
#define Bn 4
#define Cn 64
#define Hn 96
#define Wn 96
#define On 64
#define Kn 9
#define HWn (Hn*Wn)
#define TP 32          // output pixels per block (along wo)
#define NT 256         // threads per block

// wT[k][c][o] = weight[o][c][k]  (so per-k LDS staging is a contiguous copy)
__global__ void wtrans_kernel(const float* __restrict__ w, float* __restrict__ wT) {
    int i = blockIdx.x * NT + threadIdx.x;
    if (i < On * Cn * Kn) {
        int o = i / (Cn * Kn);
        int r = i - o * (Cn * Kn);
        int c = r / Kn;
        int k = r - c * Kn;
        wT[(k * Cn + c) * On + o] = w[i];
    }
}

__global__ __launch_bounds__(NT, 4) void dcn_kernel(
    const float* __restrict__ x, const float* __restrict__ offset,
    const float* __restrict__ mask, const float* __restrict__ weight,
    const float* __restrict__ bias, const float* __restrict__ wT,
    float* __restrict__ out)
{
    __shared__ float lw0[Kn*TP], lw1[Kn*TP], lw2[Kn*TP], lw3[Kn*TP];
    __shared__ int   li0[Kn*TP], li1[Kn*TP], li2[Kn*TP], li3[Kn*TP];
    __shared__ float sk[Cn][TP];     // sampled tile S_k[c][p]
    __shared__ float Wk[Cn][On];     // weight slice W_k[c][o]

    const int tid = threadIdx.x;
    const int blk = blockIdx.x;
    const int b   = blk / (Hn * (Wn / TP));
    int rem = blk - b * (Hn * (Wn / TP));
    const int ho  = rem / (Wn / TP);
    const int pt  = rem - ho * (Wn / TP);
    const int wo0 = pt * TP;

    // ---- Phase 0: per (pixel, tap) bilinear tables (validity & mask folded into weights)
    for (int e = tid; e < Kn * TP; e += NT) {
        int k = e / TP;
        int p = e - k * TP;
        int wo = wo0 + p;
        float oy = offset[((b * (2*Kn) + 2*k    ) * Hn + ho) * Wn + wo];
        float ox = offset[((b * (2*Kn) + 2*k + 1) * Hn + ho) * Wn + wo];
        float mm = mask  [((b * Kn + k) * Hn + ho) * Wn + wo];
        float py = (float)(ho - 1 + (k / 3)) + oy;
        float px = (float)(wo - 1 + (k % 3)) + ox;
        float y0f = floorf(py), x0f = floorf(px);
        float ly = py - y0f, lx = px - x0f;
        int y0 = (int)y0f, x0 = (int)x0f;
        int y1 = y0 + 1,   x1 = x0 + 1;
        float vy0 = (y0 >= 0 && y0 < Hn) ? 1.f : 0.f;
        float vy1 = (y1 >= 0 && y1 < Hn) ? 1.f : 0.f;
        float vx0 = (x0 >= 0 && x0 < Wn) ? 1.f : 0.f;
        float vx1 = (x1 >= 0 && x1 < Wn) ? 1.f : 0.f;
        int cy0 = min(max(y0, 0), Hn-1), cy1 = min(max(y1, 0), Hn-1);
        int cx0 = min(max(x0, 0), Wn-1), cx1 = min(max(x1, 0), Wn-1);
        lw0[e] = (1.f - ly) * (1.f - lx) * mm * vy0 * vx0;
        lw1[e] = (1.f - ly) * lx         * mm * vy0 * vx1;
        lw2[e] = ly         * (1.f - lx) * mm * vy1 * vx0;
        lw3[e] = ly         * lx         * mm * vy1 * vx1;
        li0[e] = cy0 * Wn + cx0;
        li1[e] = cy0 * Wn + cx1;
        li2[e] = cy1 * Wn + cx0;
        li3[e] = cy1 * Wn + cx1;
    }
    __syncthreads();

    float acc[4][2] = {};
    const int o0  = (tid >> 4) * 4;   // 16 o-groups of 4
    const int p0  = (tid & 15) * 2;   // 16 p-groups of 2
    const int sp  = tid & 31;         // gather: lane -> pixel (near-coalesced)
    const int scg = tid >> 5;         // gather: 8 channels per thread

    for (int k = 0; k < Kn; ++k) {
        // ---- stage W_k[c][o]
        if (wT) {
            const float* wsrc = wT + k * Cn * On;
            #pragma unroll
            for (int i = 0; i < (Cn * On) / NT; ++i) {
                int e2 = i * NT + tid;
                ((float*)Wk)[e2] = wsrc[e2];
            }
        } else {
            #pragma unroll
            for (int i = 0; i < (Cn * On) / NT; ++i) {
                int e2 = i * NT + tid;
                int o = e2 & (On - 1);
                int c = e2 >> 6;
                Wk[c][o] = weight[(o * Cn + c) * Kn + k];
            }
        }
        // ---- stage S_k[c][p]: bilinear gather, 8 channels per thread
        {
            int e = k * TP + sp;
            float w0 = lw0[e], w1 = lw1[e], w2 = lw2[e], w3 = lw3[e];
            int i0 = li0[e], i1 = li1[e], i2 = li2[e], i3 = li3[e];
            const float* xp = x + (size_t)(b * Cn + scg * 8) * HWn;
            #pragma unroll
            for (int j = 0; j < 8; ++j) {
                float v = w0 * xp[i0] + w1 * xp[i1] + w2 * xp[i2] + w3 * xp[i3];
                sk[scg * 8 + j][sp] = v;
                xp += HWn;
            }
        }
        __syncthreads();
        // ---- rank-64 update: out(64x32) += W_k(64x64)^T-ish * S_k(64x32)
        #pragma unroll 8
        for (int c = 0; c < Cn; ++c) {
            float4 wv = *(const float4*)&Wk[c][o0];
            float2 sv = *(const float2*)&sk[c][p0];
            acc[0][0] = fmaf(wv.x, sv.x, acc[0][0]);
            acc[0][1] = fmaf(wv.x, sv.y, acc[0][1]);
            acc[1][0] = fmaf(wv.y, sv.x, acc[1][0]);
            acc[1][1] = fmaf(wv.y, sv.y, acc[1][1]);
            acc[2][0] = fmaf(wv.z, sv.x, acc[2][0]);
            acc[2][1] = fmaf(wv.z, sv.y, acc[2][1]);
            acc[3][0] = fmaf(wv.w, sv.x, acc[3][0]);
            acc[3][1] = fmaf(wv.w, sv.y, acc[3][1]);
        }
        __syncthreads();
    }

    // ---- epilogue: bias add + coalesced float2 stores
    #pragma unroll
    for (int i = 0; i < 4; ++i) {
        float bo = bias[o0 + i];
        float2 r;
        r.x = acc[i][0] + bo;
        r.y = acc[i][1] + bo;
        *(float2*)&out[(((size_t)b * On + (o0 + i)) * Hn + ho) * Wn + wo0 + p0] = r;
    }
}

extern "C" void kernel_launch(void* const* d_in, const int* in_sizes, int n_in,
                              void* d_out, int out_size, void* d_ws, size_t ws_size,
                              hipStream_t stream) {
    const float* x      = (const float*)d_in[0];
    const float* offset = (const float*)d_in[1];
    const float* mask   = (const float*)d_in[2];
    const float* weight = (const float*)d_in[3];
    const float* bias   = (const float*)d_in[4];
    float* out = (float*)d_out;

    float* wT = nullptr;
    const size_t need = (size_t)On * Cn * Kn * sizeof(float);
    if (ws_size >= need) {
        wT = (float*)d_ws;
        wtrans_kernel<<<(On * Cn * Kn + NT - 1) / NT, NT, 0, stream>>>(weight, wT);
    }
    dcn_kernel<<<Bn * Hn * (Wn / TP), NT, 0, stream>>>(x, offset, mask, weight, bias, wT, out);
}

// Round 2
// 147.914 us; speedup vs baseline: 1.1998x; 1.1998x over previous
//
#include <hip/hip_runtime.h>

// ModulatedDeformConv2d fwd: deformable im2col (fp32 bilinear) -> bf16 MFMA GEMM.
// B=4 C=64 H=W=96 O=64 K=3x3 stride=1 pad=1 dil=1 groups=1 dg=1
#define Bn 4
#define Cn 64
#define Hn 96
#define Wn 96
#define On 64
#define Kn 9
#define HWn (Hn*Wn)
#define TP 32              // output pixels per block
#define NT 256
#define KT (Kn*Cn)         // 576 = GEMM K
#define SSTRIDE 584        // S row stride in bf16 elems (576 + 8 pad; 292 words % 32 == 4 -> conflict-free b128 phases)

typedef __attribute__((ext_vector_type(8))) short bf16x8;
typedef __attribute__((ext_vector_type(4))) float f32x4;

__device__ __forceinline__ unsigned short f2bf(float f) {
    unsigned u = __float_as_uint(f);
    u += 0x7FFFu + ((u >> 16) & 1u);   // RNE; inputs finite
    return (unsigned short)(u >> 16);
}

// Wbf[o][k*64+c] = bf16(weight[o][c][k])  -- A-fragment friendly (kappa contiguous per o)
__global__ void wtrans_kernel(const float* __restrict__ w, unsigned short* __restrict__ wbf) {
    int i = blockIdx.x * NT + threadIdx.x;
    if (i < On * KT) {
        int o = i / KT;
        int r = i - o * KT;
        int k = r >> 6;          // kappa = k*64 + c
        int c = r & 63;
        wbf[i] = f2bf(w[(o * Cn + c) * Kn + k]);
    }
}

__global__ __launch_bounds__(NT, 3) void dcn_kernel(
    const float* __restrict__ x, const float* __restrict__ offset,
    const float* __restrict__ mask, const float* __restrict__ weight,
    const float* __restrict__ bias, const unsigned short* __restrict__ wbf,
    float* __restrict__ out)
{
    __shared__ __align__(16) unsigned short Slds[TP * SSTRIDE];  // 37376 B
    __shared__ float4 lwv[Kn * TP];                              // 4608 B
    __shared__ int4   liv[Kn * TP];                              // 4608 B

    const int tid = threadIdx.x;
    // XCD swizzle: physical block p runs on XCD p%8; give each XCD a contiguous
    // (b,ho,pt) span (144 tiles = 48 rows of one batch ~ 1.2 MB x footprint -> L2-resident).
    const int p   = blockIdx.x;
    const int v   = (p & 7) * 144 + (p >> 3);
    const int b   = v / 288;
    int rem       = v - b * 288;
    const int ho  = rem / 3;
    const int pt  = rem - ho * 3;
    const int wo0 = pt * TP;

    // ---- Phase 0: bilinear tables per (tap, pixel); validity & mask folded into weights
    for (int e = tid; e < Kn * TP; e += NT) {
        int k = e >> 5;
        int pp = e & 31;
        int wo = wo0 + pp;
        float oy = offset[((b * (2*Kn) + 2*k    ) * Hn + ho) * Wn + wo];
        float ox = offset[((b * (2*Kn) + 2*k + 1) * Hn + ho) * Wn + wo];
        float mm = mask  [((b * Kn + k) * Hn + ho) * Wn + wo];
        float py = (float)(ho - 1 + (k / 3)) + oy;
        float px = (float)(wo - 1 + (k % 3)) + ox;
        float y0f = floorf(py), x0f = floorf(px);
        float ly = py - y0f, lx = px - x0f;
        int y0 = (int)y0f, x0i = (int)x0f;
        int y1 = y0 + 1,   x1i = x0i + 1;
        float vy0 = (y0  >= 0 && y0  < Hn) ? 1.f : 0.f;
        float vy1 = (y1  >= 0 && y1  < Hn) ? 1.f : 0.f;
        float vx0 = (x0i >= 0 && x0i < Wn) ? 1.f : 0.f;
        float vx1 = (x1i >= 0 && x1i < Wn) ? 1.f : 0.f;
        int cy0 = min(max(y0, 0),  Hn-1), cy1 = min(max(y1, 0),  Hn-1);
        int cx0 = min(max(x0i, 0), Wn-1), cx1 = min(max(x1i, 0), Wn-1);
        float4 wv;
        wv.x = (1.f - ly) * (1.f - lx) * mm * vy0 * vx0;
        wv.y = (1.f - ly) * lx         * mm * vy0 * vx1;
        wv.z = ly         * (1.f - lx) * mm * vy1 * vx0;
        wv.w = ly         * lx         * mm * vy1 * vx1;
        lwv[e] = wv;
        liv[e] = make_int4(cy0 * Wn + cx0, cy0 * Wn + cx1,
                           cy1 * Wn + cx0, cy1 * Wn + cx1);
    }
    __syncthreads();

    // ---- Phase 1: gather all 9 taps -> Slds[p][k*64+c] (bf16)
    {
        const int sp  = tid & 31;   // pixel (lane-coalesced x addresses)
        const int scg = tid >> 5;   // channel group: 8 channels each
        const float* xp0 = x + ((size_t)b * Cn + scg * 8) * HWn;
        #pragma unroll
        for (int k = 0; k < Kn; ++k) {
            float4 wv = lwv[k * TP + sp];
            int4   iv = liv[k * TP + sp];
            unsigned short h[8];
            #pragma unroll
            for (int j = 0; j < 8; ++j) {
                const float* xp = xp0 + (size_t)j * HWn;
                float val = wv.x * xp[iv.x] + wv.y * xp[iv.y]
                          + wv.z * xp[iv.z] + wv.w * xp[iv.w];
                h[j] = f2bf(val);
            }
            uint4 pk;
            pk.x = h[0] | ((unsigned)h[1] << 16);
            pk.y = h[2] | ((unsigned)h[3] << 16);
            pk.z = h[4] | ((unsigned)h[5] << 16);
            pk.w = h[6] | ((unsigned)h[7] << 16);
            *(uint4*)&Slds[sp * SSTRIDE + k * 64 + scg * 8] = pk;
        }
    }
    __syncthreads();

    // ---- Phase 2: GEMM. Wave w: o-rows [16w,16w+16), both 16-px tiles, K=576 in 18 steps.
    const int wave = tid >> 6;
    const int lane = tid & 63;
    const int m    = lane & 15;
    const int quad = lane >> 4;
    const int o    = wave * 16 + m;

    f32x4 acc0 = {0.f, 0.f, 0.f, 0.f};
    f32x4 acc1 = {0.f, 0.f, 0.f, 0.f};

    if (wbf) {
        const unsigned short* arow = wbf + (size_t)o * KT;
        #pragma unroll 3
        for (int t = 0; t < KT / 32; ++t) {
            const int kb = t * 32 + quad * 8;
            bf16x8 a  = *(const bf16x8*)(arow + kb);
            bf16x8 b0 = *(const bf16x8*)&Slds[m * SSTRIDE + kb];
            bf16x8 b1 = *(const bf16x8*)&Slds[(16 + m) * SSTRIDE + kb];
            acc0 = __builtin_amdgcn_mfma_f32_16x16x32_bf16(a, b0, acc0, 0, 0, 0);
            acc1 = __builtin_amdgcn_mfma_f32_16x16x32_bf16(a, b1, acc1, 0, 0, 0);
        }
    } else {
        // fallback: convert W on the fly from original [o][c][k] layout
        #pragma unroll 2
        for (int t = 0; t < KT / 32; ++t) {
            const int kb = t * 32 + quad * 8;
            const int k = kb >> 6, c0 = kb & 63;
            bf16x8 a;
            #pragma unroll
            for (int j = 0; j < 8; ++j)
                a[j] = (short)f2bf(weight[(o * Cn + c0 + j) * Kn + k]);
            bf16x8 b0 = *(const bf16x8*)&Slds[m * SSTRIDE + kb];
            bf16x8 b1 = *(const bf16x8*)&Slds[(16 + m) * SSTRIDE + kb];
            acc0 = __builtin_amdgcn_mfma_f32_16x16x32_bf16(a, b0, acc0, 0, 0, 0);
            acc1 = __builtin_amdgcn_mfma_f32_16x16x32_bf16(a, b1, acc1, 0, 0, 0);
        }
    }

    // ---- Epilogue: C/D layout col=lane&15, row=quad*4+reg. Coalesced 16-float runs.
    #pragma unroll
    for (int r = 0; r < 4; ++r) {
        int oo = (tid >> 6) * 16 + quad * 4 + r;
        float bb = bias[oo];
        size_t base = (((size_t)b * On + oo) * Hn + ho) * Wn + wo0;
        out[base + m]      = acc0[r] + bb;
        out[base + 16 + m] = acc1[r] + bb;
    }
}

extern "C" void kernel_launch(void* const* d_in, const int* in_sizes, int n_in,
                              void* d_out, int out_size, void* d_ws, size_t ws_size,
                              hipStream_t stream) {
    const float* x      = (const float*)d_in[0];
    const float* offset = (const float*)d_in[1];
    const float* mask   = (const float*)d_in[2];
    const float* weight = (const float*)d_in[3];
    const float* bias   = (const float*)d_in[4];
    float* out = (float*)d_out;

    unsigned short* wbf = nullptr;
    const size_t need = (size_t)On * KT * sizeof(unsigned short);
    if (ws_size >= need) {
        wbf = (unsigned short*)d_ws;
        wtrans_kernel<<<(On * KT + NT - 1) / NT, NT, 0, stream>>>(weight, wbf);
    }
    dcn_kernel<<<Bn * Hn * (Wn / TP), NT, 0, stream>>>(x, offset, mask, weight, bias, wbf, out);
}

// Round 3
// 96.162 us; speedup vs baseline: 1.8456x; 1.5382x over previous
//
#include <hip/hip_runtime.h>

// ModulatedDeformConv2d fwd: NHWC-bf16 x transpose -> wide coalesced bilinear
// gather (software-pipelined) -> bf16 MFMA GEMM.
// B=4 C=64 H=W=96 O=64 K=3x3 stride=1 pad=1 dil=1 groups=1 dg=1
#define Bn 4
#define Cn 64
#define Hn 96
#define Wn 96
#define On 64
#define Kn 9
#define HWn (Hn*Wn)
#define TP 32              // output pixels per block
#define NT 256
#define KT (Kn*Cn)         // 576 = GEMM K
#define SSTRIDE 584        // S row stride in bf16 elems (576 + 8 pad)

typedef __attribute__((ext_vector_type(8))) short bf16x8;
typedef __attribute__((ext_vector_type(4))) float f32x4;

__device__ __forceinline__ unsigned short f2bf(float f) {
    unsigned u = __float_as_uint(f);
    u += 0x7FFFu + ((u >> 16) & 1u);   // RNE; inputs finite
    return (unsigned short)(u >> 16);
}
__device__ __forceinline__ float bf2f(unsigned short h) {
    return __uint_as_float((unsigned)h << 16);
}

// Wbf[o][k*64+c] = bf16(weight[o][c][k])  -- A-fragment friendly
__global__ void wtrans_kernel(const float* __restrict__ w, unsigned short* __restrict__ wbf) {
    int i = blockIdx.x * NT + threadIdx.x;
    if (i < On * KT) {
        int o = i / KT;
        int r = i - o * KT;
        int k = r >> 6;
        int c = r & 63;
        wbf[i] = f2bf(w[(o * Cn + c) * Kn + k]);
    }
}

// xT[b][h][w][c] = bf16(x[b][c][h][w])  (NHWC: one bilinear neighbor = 128 contiguous bytes)
__global__ __launch_bounds__(NT) void xtrans_kernel(const float* __restrict__ x,
                                                    unsigned short* __restrict__ xT) {
    __shared__ unsigned short tile[Cn * Wn];   // 12 KB
    const int tid = threadIdx.x;
    const int b = blockIdx.x / Hn;
    const int h = blockIdx.x - b * Hn;
    #pragma unroll
    for (int i = 0; i < (Cn * Wn) / NT; ++i) {      // 24: coalesced w-major reads
        int e = i * NT + tid;
        int c = e / Wn, w = e - c * Wn;
        tile[c * Wn + w] = f2bf(x[(((size_t)b * Cn + c) * Hn + h) * Wn + w]);
    }
    __syncthreads();
    #pragma unroll
    for (int i = 0; i < (Wn * 8) / NT; ++i) {       // 3: coalesced 16B writes
        int s = i * NT + tid;
        int w = s >> 3, g = s & 7;
        unsigned short hh[8];
        #pragma unroll
        for (int j = 0; j < 8; ++j) hh[j] = tile[(g * 8 + j) * Wn + w];
        uint4 pk;
        pk.x = hh[0] | ((unsigned)hh[1] << 16);
        pk.y = hh[2] | ((unsigned)hh[3] << 16);
        pk.z = hh[4] | ((unsigned)hh[5] << 16);
        pk.w = hh[6] | ((unsigned)hh[7] << 16);
        *(uint4*)&xT[(((size_t)b * Hn + h) * Wn + w) * Cn + g * 8] = pk;
    }
}

template <bool NHWC>
__global__ __launch_bounds__(NT, 3) void dcn_kernel(
    const float* __restrict__ x, const unsigned short* __restrict__ xT,
    const float* __restrict__ offset, const float* __restrict__ mask,
    const float* __restrict__ weight, const float* __restrict__ bias,
    const unsigned short* __restrict__ wbf, float* __restrict__ out)
{
    __shared__ __align__(16) unsigned short Slds[TP * SSTRIDE];  // 37376 B
    __shared__ float4 lwv[Kn * TP];                              // 4608 B
    __shared__ int4   liv[Kn * TP];                              // 4608 B

    const int tid = threadIdx.x;
    // XCD swizzle: each XCD owns a contiguous 144-tile span (~1.2 MB x footprint -> L2-resident)
    const int p   = blockIdx.x;
    const int v   = (p & 7) * 144 + (p >> 3);
    const int b   = v / 288;
    int rem       = v - b * 288;
    const int ho  = rem / 3;
    const int pt  = rem - ho * 3;
    const int wo0 = pt * TP;

    // ---- Phase 0: bilinear tables per (tap, pixel); validity & mask folded into weights
    for (int e = tid; e < Kn * TP; e += NT) {
        int k = e >> 5;
        int pp = e & 31;
        int wo = wo0 + pp;
        float oy = offset[((b * (2*Kn) + 2*k    ) * Hn + ho) * Wn + wo];
        float ox = offset[((b * (2*Kn) + 2*k + 1) * Hn + ho) * Wn + wo];
        float mm = mask  [((b * Kn + k) * Hn + ho) * Wn + wo];
        float py = (float)(ho - 1 + (k / 3)) + oy;
        float px = (float)(wo - 1 + (k % 3)) + ox;
        float y0f = floorf(py), x0f = floorf(px);
        float ly = py - y0f, lx = px - x0f;
        int y0 = (int)y0f, x0i = (int)x0f;
        int y1 = y0 + 1,   x1i = x0i + 1;
        float vy0 = (y0  >= 0 && y0  < Hn) ? 1.f : 0.f;
        float vy1 = (y1  >= 0 && y1  < Hn) ? 1.f : 0.f;
        float vx0 = (x0i >= 0 && x0i < Wn) ? 1.f : 0.f;
        float vx1 = (x1i >= 0 && x1i < Wn) ? 1.f : 0.f;
        int cy0 = min(max(y0, 0),  Hn-1), cy1 = min(max(y1, 0),  Hn-1);
        int cx0 = min(max(x0i, 0), Wn-1), cx1 = min(max(x1i, 0), Wn-1);
        float4 wv;
        wv.x = (1.f - ly) * (1.f - lx) * mm * vy0 * vx0;
        wv.y = (1.f - ly) * lx         * mm * vy0 * vx1;
        wv.z = ly         * (1.f - lx) * mm * vy1 * vx0;
        wv.w = ly         * lx         * mm * vy1 * vx1;
        lwv[e] = wv;
        liv[e] = make_int4(cy0 * Wn + cx0, cy0 * Wn + cx1,
                           cy1 * Wn + cx0, cy1 * Wn + cx1);
    }
    __syncthreads();

    // ---- Phase 1: deformable im2col gather -> Slds[p][k*64+c] (bf16)
    if (NHWC) {
        // 8 threads per pixel; each owns channel octet g. 4x16B loads per tap,
        // next tap prefetched while current combines (>=8 loads in flight).
        const int pp = tid >> 3;     // pixel 0..31
        const int g  = tid & 7;      // channel octet
        const unsigned short* xb = xT + (size_t)b * HWn * Cn + g * 8;

        bf16x8 c0, c1, c2, c3, n0, n1, n2, n3;
        int4 iv = liv[pp];
        c0 = *(const bf16x8*)(xb + ((size_t)iv.x << 6));
        c1 = *(const bf16x8*)(xb + ((size_t)iv.y << 6));
        c2 = *(const bf16x8*)(xb + ((size_t)iv.z << 6));
        c3 = *(const bf16x8*)(xb + ((size_t)iv.w << 6));
        #pragma unroll
        for (int k = 0; k < Kn; ++k) {
            if (k < Kn - 1) {
                int4 nv = liv[(k + 1) * TP + pp];
                n0 = *(const bf16x8*)(xb + ((size_t)nv.x << 6));
                n1 = *(const bf16x8*)(xb + ((size_t)nv.y << 6));
                n2 = *(const bf16x8*)(xb + ((size_t)nv.z << 6));
                n3 = *(const bf16x8*)(xb + ((size_t)nv.w << 6));
            }
            float4 wv = lwv[k * TP + pp];
            unsigned short hh[8];
            #pragma unroll
            for (int j = 0; j < 8; ++j) {
                float r = wv.x * bf2f((unsigned short)c0[j])
                        + wv.y * bf2f((unsigned short)c1[j])
                        + wv.z * bf2f((unsigned short)c2[j])
                        + wv.w * bf2f((unsigned short)c3[j]);
                hh[j] = f2bf(r);
            }
            uint4 pk;
            pk.x = hh[0] | ((unsigned)hh[1] << 16);
            pk.y = hh[2] | ((unsigned)hh[3] << 16);
            pk.z = hh[4] | ((unsigned)hh[5] << 16);
            pk.w = hh[6] | ((unsigned)hh[7] << 16);
            *(uint4*)&Slds[pp * SSTRIDE + k * 64 + g * 8] = pk;
            c0 = n0; c1 = n1; c2 = n2; c3 = n3;
        }
    } else {
        // fallback: scalar gather from NCHW fp32 x
        const int sp  = tid & 31;
        const int scg = tid >> 5;
        const float* xp0 = x + ((size_t)b * Cn + scg * 8) * HWn;
        #pragma unroll
        for (int k = 0; k < Kn; ++k) {
            float4 wv = lwv[k * TP + sp];
            int4   iv = liv[k * TP + sp];
            unsigned short h8[8];
            #pragma unroll
            for (int j = 0; j < 8; ++j) {
                const float* xp = xp0 + (size_t)j * HWn;
                float val = wv.x * xp[iv.x] + wv.y * xp[iv.y]
                          + wv.z * xp[iv.z] + wv.w * xp[iv.w];
                h8[j] = f2bf(val);
            }
            uint4 pk;
            pk.x = h8[0] | ((unsigned)h8[1] << 16);
            pk.y = h8[2] | ((unsigned)h8[3] << 16);
            pk.z = h8[4] | ((unsigned)h8[5] << 16);
            pk.w = h8[6] | ((unsigned)h8[7] << 16);
            *(uint4*)&Slds[sp * SSTRIDE + k * 64 + scg * 8] = pk;
        }
    }
    __syncthreads();

    // ---- Phase 2: GEMM. Wave w: o-rows [16w,16w+16), two 16-px tiles, K=576 in 18 steps.
    const int wave = tid >> 6;
    const int lane = tid & 63;
    const int m    = lane & 15;
    const int quad = lane >> 4;
    const int o    = wave * 16 + m;

    f32x4 acc0 = {0.f, 0.f, 0.f, 0.f};
    f32x4 acc1 = {0.f, 0.f, 0.f, 0.f};

    if (wbf) {
        const unsigned short* arow = wbf + (size_t)o * KT;
        #pragma unroll 3
        for (int t = 0; t < KT / 32; ++t) {
            const int kb = t * 32 + quad * 8;
            bf16x8 a  = *(const bf16x8*)(arow + kb);
            bf16x8 b0 = *(const bf16x8*)&Slds[m * SSTRIDE + kb];
            bf16x8 b1 = *(const bf16x8*)&Slds[(16 + m) * SSTRIDE + kb];
            acc0 = __builtin_amdgcn_mfma_f32_16x16x32_bf16(a, b0, acc0, 0, 0, 0);
            acc1 = __builtin_amdgcn_mfma_f32_16x16x32_bf16(a, b1, acc1, 0, 0, 0);
        }
    } else {
        #pragma unroll 2
        for (int t = 0; t < KT / 32; ++t) {
            const int kb = t * 32 + quad * 8;
            const int k = kb >> 6, cc0 = kb & 63;
            bf16x8 a;
            #pragma unroll
            for (int j = 0; j < 8; ++j)
                a[j] = (short)f2bf(weight[(o * Cn + cc0 + j) * Kn + k]);
            bf16x8 b0 = *(const bf16x8*)&Slds[m * SSTRIDE + kb];
            bf16x8 b1 = *(const bf16x8*)&Slds[(16 + m) * SSTRIDE + kb];
            acc0 = __builtin_amdgcn_mfma_f32_16x16x32_bf16(a, b0, acc0, 0, 0, 0);
            acc1 = __builtin_amdgcn_mfma_f32_16x16x32_bf16(a, b1, acc1, 0, 0, 0);
        }
    }

    // ---- Epilogue: C/D layout col=lane&15, row=quad*4+reg.
    #pragma unroll
    for (int r = 0; r < 4; ++r) {
        int oo = wave * 16 + quad * 4 + r;
        float bb = bias[oo];
        size_t base = (((size_t)b * On + oo) * Hn + ho) * Wn + wo0;
        out[base + m]      = acc0[r] + bb;
        out[base + 16 + m] = acc1[r] + bb;
    }
}

extern "C" void kernel_launch(void* const* d_in, const int* in_sizes, int n_in,
                              void* d_out, int out_size, void* d_ws, size_t ws_size,
                              hipStream_t stream) {
    const float* x      = (const float*)d_in[0];
    const float* offset = (const float*)d_in[1];
    const float* mask   = (const float*)d_in[2];
    const float* weight = (const float*)d_in[3];
    const float* bias   = (const float*)d_in[4];
    float* out = (float*)d_out;

    const size_t xt_bytes = (size_t)Bn * HWn * Cn * sizeof(unsigned short);  // 4718592
    const size_t w_bytes  = (size_t)On * KT * sizeof(unsigned short);        // 73728

    unsigned short* xT  = nullptr;
    unsigned short* wbf = nullptr;
    if (ws_size >= xt_bytes + w_bytes) {
        xT  = (unsigned short*)d_ws;
        wbf = (unsigned short*)((char*)d_ws + xt_bytes);
    } else if (ws_size >= w_bytes) {
        wbf = (unsigned short*)d_ws;
    }

    if (wbf) wtrans_kernel<<<(On * KT + NT - 1) / NT, NT, 0, stream>>>(weight, wbf);
    if (xT) {
        xtrans_kernel<<<Bn * Hn, NT, 0, stream>>>(x, xT);
        dcn_kernel<true><<<Bn * Hn * (Wn / TP), NT, 0, stream>>>(
            x, xT, offset, mask, weight, bias, wbf, out);
    } else {
        dcn_kernel<false><<<Bn * Hn * (Wn / TP), NT, 0, stream>>>(
            x, nullptr, offset, mask, weight, bias, wbf, out);
    }
}